// Round 3
// baseline (11666.817 us; speedup 1.0000x reference)
//
#include <hip/hip_runtime.h>
#include <math.h>

// ---------------------------------------------------------------------------
// MultiModalImputer forward, all-f32.
// R2 change: gru_scan rewritten — full Whh row in VGPRs (no per-step global
// W traffic), 4 independent accumulators (break 192-deep FMA dep chain),
// xv prefetch one step ahead (hide HBM latency under the dot).
// ---------------------------------------------------------------------------

constexpr int N_   = 16;
constexpr int L_   = 1024;
constexpr int D_   = 12;
constexpr int E_   = 8;
constexpr int HID_ = 16;
constexpr int ADM_ = 64;
constexpr int H_   = 192;   // HID*D
constexpr int H3_  = 576;   // 3*H
constexpr int IN0_ = 96;    // D*E
constexpr int IN1_ = 384;   // 2*H
constexpr int NL_  = N_ * L_;  // 16384
constexpr int FFH_ = 512;

#define F4(p) (*(const float4*)(p))

// ---------------- K1: adm MLP: relu(adm@W1.T+b1)@W2.T+b2 -> [16,16] --------
__global__ void adm_mlp_kernel(const float* __restrict__ adm,
                               const float* __restrict__ W1, const float* __restrict__ b1,
                               const float* __restrict__ W2, const float* __restrict__ b2,
                               float* __restrict__ adm_out) {
  __shared__ float hid[N_][HID_];
  const int t = threadIdx.x;        // 256
  const int n = t >> 4, j = t & 15;
  float acc = b1[j];
  for (int k = 0; k < ADM_; ++k) acc = fmaf(adm[n * ADM_ + k], W1[j * ADM_ + k], acc);
  hid[n][j] = fmaxf(acc, 0.f);
  __syncthreads();
  float acc2 = b2[j];
  for (int k = 0; k < HID_; ++k) acc2 = fmaf(hid[n][k], W2[j * HID_ + k], acc2);
  adm_out[n * HID_ + j] = acc2;
}

// ---------------- K2: fused mask-embedding + per-channel Linear(1->8) ------
__global__ void embed_kernel(const float* __restrict__ series, const int* __restrict__ mask,
                             const float* __restrict__ sW, const float* __restrict__ membW,
                             float* __restrict__ emb) {
  const int i = blockIdx.x * blockDim.x + threadIdx.x;   // over NL*96
  if (i >= NL_ * IN0_) return;
  const int de = i % IN0_;
  const int nl = i / IN0_;
  const int d = de >> 3, e = de & 7;
  const float s = series[nl * D_ + d];
  const int   m = mask[nl * D_ + d];
  const int idx = m ? (d + 1) : 0;
  emb[i] = membW[idx * E_ + e] + s * sW[de];
}

// ---------------- K3: pack Whh [576][192] -> [48][576][4] for coalescing ---
__global__ void whh_pack_kernel(const float* __restrict__ Whh, float* __restrict__ Wp) {
  const int i = blockIdx.x * blockDim.x + threadIdx.x;   // 576*192 = 110592
  if (i >= H3_ * H_) return;
  const int j = i / H_, k = i % H_;
  const int kc = k >> 2, c = k & 3;
  Wp[((size_t)kc * H3_ + j) * 4 + c] = Whh[i];
}

// ---------------- K4: xp GEMM: xp[dir][row][j] = A@W^T + bih ---------------
// A [NL][K] row-major, Wf/Wb [576][K] row-major. BM=BN=128, BK=16, 8x8/thread.
__global__ __launch_bounds__(256)
void xp_gemm_kernel(const float* __restrict__ A, const int K,
                    const float* __restrict__ Wf, const float* __restrict__ Wb,
                    const float* __restrict__ bf, const float* __restrict__ bb,
                    float* __restrict__ xp /* [2][NL][576] */) {
  constexpr int BM = 128, BN = 128, BK = 16, TM = 8, TN = 8;
  __shared__ float As[BK][BM + 4];
  __shared__ float Bs[BK][BN + 4];
  const int bm = blockIdx.x;   // 128
  const int bn = blockIdx.y;   // 9
  const int t = threadIdx.x;
  const int tx = t & 15, ty = t >> 4;
  const int row0 = bm * BM, col0 = bn * BN;
  float acc[TM][TN] = {};

  for (int k0 = 0; k0 < K; k0 += BK) {
    #pragma unroll
    for (int r = 0; r < 2; ++r) {
      const int li = t + r * 256;
      const int i = li >> 2;
      const int kc = (li & 3) << 2;
      float4 v = F4(A + (size_t)(row0 + i) * K + k0 + kc);
      As[kc + 0][i] = v.x; As[kc + 1][i] = v.y; As[kc + 2][i] = v.z; As[kc + 3][i] = v.w;
    }
    #pragma unroll
    for (int r = 0; r < 2; ++r) {
      const int li = t + r * 256;
      const int jj = li >> 2;
      const int kc = (li & 3) << 2;
      const int col = col0 + jj;
      const float* W = (col < H3_) ? Wf : Wb;
      const int wrow = (col < H3_) ? col : col - H3_;
      float4 v = F4(W + (size_t)wrow * K + k0 + kc);
      Bs[kc + 0][jj] = v.x; Bs[kc + 1][jj] = v.y; Bs[kc + 2][jj] = v.z; Bs[kc + 3][jj] = v.w;
    }
    __syncthreads();
    #pragma unroll
    for (int kk = 0; kk < BK; ++kk) {
      float a[TM], b[TN];
      const float4* a4 = (const float4*)&As[kk][ty * TM];
      const float4* b4 = (const float4*)&Bs[kk][tx * TN];
      float4 av0 = a4[0], av1 = a4[1], bv0 = b4[0], bv1 = b4[1];
      a[0]=av0.x; a[1]=av0.y; a[2]=av0.z; a[3]=av0.w; a[4]=av1.x; a[5]=av1.y; a[6]=av1.z; a[7]=av1.w;
      b[0]=bv0.x; b[1]=bv0.y; b[2]=bv0.z; b[3]=bv0.w; b[4]=bv1.x; b[5]=bv1.y; b[6]=bv1.z; b[7]=bv1.w;
      #pragma unroll
      for (int i = 0; i < TM; ++i)
        #pragma unroll
        for (int jq = 0; jq < TN; ++jq) acc[i][jq] = fmaf(a[i], b[jq], acc[i][jq]);
    }
    __syncthreads();
  }
  #pragma unroll
  for (int i = 0; i < TM; ++i) {
    const int row = row0 + ty * TM + i;
    #pragma unroll
    for (int jq = 0; jq < TN; ++jq) {
      const int col = col0 + tx * TN + jq;
      const int dir = (col >= H3_);
      const int jj = col - dir * H3_;
      const float bias = dir ? bb[jj] : bf[jj];
      xp[((size_t)dir * NL_ + row) * H3_ + jj] = acc[i][jq] + bias;
    }
  }
}

// ---------------- K5: GRU scan. One block per (dir, batch). 576 threads. ---
// Whole Whh row (192 f32) register-resident; 4 accumulators; xv prefetch.
__global__ __launch_bounds__(H3_, 1)
void gru_scan_kernel(const float* __restrict__ xp,      // [2][NL][576]
                     const float* __restrict__ Wpf,     // packed [48][576][4]
                     const float* __restrict__ Wpb,
                     const float* __restrict__ bhf,
                     const float* __restrict__ bhb,
                     float* __restrict__ hcat) {        // [NL][384]
  const int dir = blockIdx.x >> 4;
  const int n   = blockIdx.x & 15;
  const float* __restrict__ xpd = xp + ((size_t)dir * NL_ + (size_t)n * L_) * H3_;
  const float* __restrict__ Wp  = dir ? Wpb : Wpf;
  const float* __restrict__ bh  = dir ? bhb : bhf;
  float* __restrict__ outd = hcat + (size_t)n * L_ * IN1_ + dir * H_;

  const int j = threadIdx.x;   // 0..575

  __shared__ __align__(16) float h_lds[H_];
  __shared__ float gh_lds[H3_];
  __shared__ float xn_lds[H_];

  // full row j of packed Whh in registers: w[4*kc+c] = Whh[j][4*kc+c]
  float w[192];
  #pragma unroll
  for (int kc = 0; kc < 48; ++kc) {
    float4 v = F4(Wp + ((size_t)kc * H3_ + j) * 4);
    w[4*kc+0] = v.x; w[4*kc+1] = v.y; w[4*kc+2] = v.z; w[4*kc+3] = v.w;
  }
  const float bj = bh[j];
  if (j < H_) h_lds[j] = 0.f;
  __syncthreads();

  const float4* __restrict__ h4 = (const float4*)h_lds;

  const int tstep = dir ? -1 : 1;
  int t = dir ? (L_ - 1) : 0;
  float xv = xpd[(size_t)t * H3_ + j];          // prefetched current step

  for (int tt = 0; tt < L_; ++tt) {
    // prefetch next step's xv (uniform branch; hidden under the dot below)
    float xv_next = 0.f;
    if (tt + 1 < L_) xv_next = xpd[(size_t)(t + tstep) * H3_ + j];

    float a0 = bj, a1 = 0.f, a2 = 0.f, a3 = 0.f;
    #pragma unroll
    for (int kc = 0; kc < 48; kc += 4) {
      float4 h0 = h4[kc + 0];
      a0 = fmaf(w[4*kc+ 0], h0.x, a0);
      a0 = fmaf(w[4*kc+ 1], h0.y, a0);
      a0 = fmaf(w[4*kc+ 2], h0.z, a0);
      a0 = fmaf(w[4*kc+ 3], h0.w, a0);
      float4 h1 = h4[kc + 1];
      a1 = fmaf(w[4*kc+ 4], h1.x, a1);
      a1 = fmaf(w[4*kc+ 5], h1.y, a1);
      a1 = fmaf(w[4*kc+ 6], h1.z, a1);
      a1 = fmaf(w[4*kc+ 7], h1.w, a1);
      float4 h2 = h4[kc + 2];
      a2 = fmaf(w[4*kc+ 8], h2.x, a2);
      a2 = fmaf(w[4*kc+ 9], h2.y, a2);
      a2 = fmaf(w[4*kc+10], h2.z, a2);
      a2 = fmaf(w[4*kc+11], h2.w, a2);
      float4 h3 = h4[kc + 3];
      a3 = fmaf(w[4*kc+12], h3.x, a3);
      a3 = fmaf(w[4*kc+13], h3.y, a3);
      a3 = fmaf(w[4*kc+14], h3.z, a3);
      a3 = fmaf(w[4*kc+15], h3.w, a3);
    }
    float acc = (a0 + a1) + (a2 + a3);

    if (j < 2 * H_) acc += xv;
    gh_lds[j] = acc;
    if (j >= 2 * H_) xn_lds[j - 2 * H_] = xv;
    __syncthreads();
    if (j < H_) {
      const float r  = 1.f / (1.f + __expf(-gh_lds[j]));
      const float z  = 1.f / (1.f + __expf(-gh_lds[H_ + j]));
      const float nn = tanhf(xn_lds[j] + r * gh_lds[2 * H_ + j]);
      const float hnew = (1.f - z) * nn + z * h_lds[j];
      h_lds[j] = hnew;                       // dot-reads finished at barrier above
      outd[(size_t)t * IN1_ + j] = hnew;
    }
    __syncthreads();

    xv = xv_next;
    t += tstep;
  }
}

// ---------------- K6: fused per-channel FFN + LayerNorm + ReLU + Linear ----
// Block: (d, 128 rows). 256 threads; thread owns W1 rows t and t+256 in regs.
__global__ __launch_bounds__(256)
void ffn_kernel(const float* __restrict__ hcat, const float* __restrict__ adm_out,
                const float* __restrict__ W1, const float* __restrict__ b1,
                const float* __restrict__ lng, const float* __restrict__ lnb,
                const float* __restrict__ W2, const float* __restrict__ b2,
                float* __restrict__ out) {
  constexpr int FROWS = 8;
  const int d = blockIdx.y;            // 12
  const int row_base = blockIdx.x * 128;
  const int t = threadIdx.x;
  const int lane = t & 63, w = t >> 6;

  __shared__ __align__(16) float featL[FROWS][48];
  __shared__ __align__(16) float hhL[FROWS][FFH_];
  __shared__ float gL[FFH_], bLn[FFH_], w2L[FFH_], b1L[FFH_];

  for (int i = t; i < FFH_; i += 256) {
    gL[i]  = lng[d * FFH_ + i];
    bLn[i] = lnb[d * FFH_ + i];
    w2L[i] = W2[d * FFH_ + i];
    b1L[i] = b1[d * FFH_ + i];
  }
  float w1a[48], w1b[48];
  {
    const float* ra = W1 + ((size_t)d * FFH_ + t) * 48;
    const float* rb = W1 + ((size_t)d * FFH_ + 256 + t) * 48;
    #pragma unroll
    for (int kc = 0; kc < 12; ++kc) {
      float4 va = F4(ra + kc * 4);
      w1a[4*kc+0]=va.x; w1a[4*kc+1]=va.y; w1a[4*kc+2]=va.z; w1a[4*kc+3]=va.w;
      float4 vb = F4(rb + kc * 4);
      w1b[4*kc+0]=vb.x; w1b[4*kc+1]=vb.y; w1b[4*kc+2]=vb.z; w1b[4*kc+3]=vb.w;
    }
  }
  const float b2v = b2[d];
  __syncthreads();

  for (int c0 = 0; c0 < 128; c0 += FROWS) {
    for (int idx = t; idx < FROWS * 48; idx += 256) {
      const int r = idx / 48, k = idx % 48;
      const int row = row_base + c0 + r;
      float v;
      if (k < 32) v = hcat[(size_t)row * IN1_ + d * 32 + k];
      else        v = adm_out[(row >> 10) * HID_ + (k - 32)];
      featL[r][k] = v;
    }
    __syncthreads();
    float acc_a[FROWS] = {}, acc_b[FROWS] = {};
    #pragma unroll
    for (int r = 0; r < FROWS; ++r) {
      const float4* f4 = (const float4*)featL[r];
      #pragma unroll
      for (int kc = 0; kc < 12; ++kc) {
        float4 f = f4[kc];
        acc_a[r] = fmaf(w1a[4*kc+0], f.x, acc_a[r]);
        acc_a[r] = fmaf(w1a[4*kc+1], f.y, acc_a[r]);
        acc_a[r] = fmaf(w1a[4*kc+2], f.z, acc_a[r]);
        acc_a[r] = fmaf(w1a[4*kc+3], f.w, acc_a[r]);
        acc_b[r] = fmaf(w1b[4*kc+0], f.x, acc_b[r]);
        acc_b[r] = fmaf(w1b[4*kc+1], f.y, acc_b[r]);
        acc_b[r] = fmaf(w1b[4*kc+2], f.z, acc_b[r]);
        acc_b[r] = fmaf(w1b[4*kc+3], f.w, acc_b[r]);
      }
    }
    #pragma unroll
    for (int r = 0; r < FROWS; ++r) {
      hhL[r][t]       = acc_a[r] + b1L[t];
      hhL[r][t + 256] = acc_b[r] + b1L[t + 256];
    }
    __syncthreads();
    // LayerNorm + ReLU + W2 reduce: wave w handles rows w and w+4
    #pragma unroll
    for (int rr = 0; rr < 2; ++rr) {
      const int r = w + rr * 4;
      const float4* h4 = (const float4*)hhL[r];
      float4 x0 = h4[lane * 2], x1 = h4[lane * 2 + 1];
      float s = x0.x + x0.y + x0.z + x0.w + x1.x + x1.y + x1.z + x1.w;
      float q = x0.x*x0.x + x0.y*x0.y + x0.z*x0.z + x0.w*x0.w
              + x1.x*x1.x + x1.y*x1.y + x1.z*x1.z + x1.w*x1.w;
      #pragma unroll
      for (int m = 1; m < 64; m <<= 1) { s += __shfl_xor(s, m); q += __shfl_xor(q, m); }
      const float mu   = s * (1.f / FFH_);
      const float var  = q * (1.f / FFH_) - mu * mu;
      const float rstd = rsqrtf(var + 1e-5f);
      const int col = lane * 8;
      const float xs[8] = {x0.x, x0.y, x0.z, x0.w, x1.x, x1.y, x1.z, x1.w};
      float o = 0.f;
      #pragma unroll
      for (int i = 0; i < 8; ++i) {
        float v = (xs[i] - mu) * rstd * gL[col + i] + bLn[col + i];
        v = fmaxf(v, 0.f);
        o = fmaf(v, w2L[col + i], o);
      }
      #pragma unroll
      for (int m = 1; m < 64; m <<= 1) o += __shfl_xor(o, m);
      if (lane == 0) {
        const int row = row_base + c0 + r;
        out[(size_t)row * D_ + d] = o + b2v;
      }
    }
    __syncthreads();
  }
}

// ---------------------------------------------------------------------------
extern "C" void kernel_launch(void* const* d_in, const int* in_sizes, int n_in,
                              void* d_out, int out_size, void* d_ws, size_t ws_size,
                              hipStream_t stream) {
  const float* series = (const float*)d_in[0];
  const float* adm    = (const float*)d_in[1];
  const int*   mask   = (const int*)  d_in[2];
  const float* sW     = (const float*)d_in[3];
  const float* membW  = (const float*)d_in[4];
  const float* aW1    = (const float*)d_in[5];
  const float* ab1    = (const float*)d_in[6];
  const float* aW2    = (const float*)d_in[7];
  const float* ab2    = (const float*)d_in[8];
  const float* Wih0f  = (const float*)d_in[9];
  const float* Whh0f  = (const float*)d_in[10];
  const float* bih0f  = (const float*)d_in[11];
  const float* bhh0f  = (const float*)d_in[12];
  const float* Wih0b  = (const float*)d_in[13];
  const float* Whh0b  = (const float*)d_in[14];
  const float* bih0b  = (const float*)d_in[15];
  const float* bhh0b  = (const float*)d_in[16];
  const float* Wih1f  = (const float*)d_in[17];
  const float* Whh1f  = (const float*)d_in[18];
  const float* bih1f  = (const float*)d_in[19];
  const float* bhh1f  = (const float*)d_in[20];
  const float* Wih1b  = (const float*)d_in[21];
  const float* Whh1b  = (const float*)d_in[22];
  const float* bih1b  = (const float*)d_in[23];
  const float* bhh1b  = (const float*)d_in[24];
  const float* ffnW1  = (const float*)d_in[25];
  const float* ffnb1  = (const float*)d_in[26];
  const float* lng    = (const float*)d_in[27];
  const float* lnb    = (const float*)d_in[28];
  const float* ffnW2  = (const float*)d_in[29];
  const float* ffnb2  = (const float*)d_in[30];
  float* outp = (float*)d_out;

  // workspace layout (floats): ~104 MiB total
  float* ws      = (float*)d_ws;
  float* adm_out = ws;                                   // 256
  float* emb     = adm_out + 256;                        // NL*96   = 1,572,864
  float* xp      = emb + (size_t)NL_ * IN0_;             // 2*NL*576= 18,874,368
  float* hcat    = xp + (size_t)2 * NL_ * H3_;           // NL*384  = 6,291,456
  float* wp0f    = hcat + (size_t)NL_ * IN1_;            // 110,592 each
  float* wp0b    = wp0f + (size_t)H3_ * H_;
  float* wp1f    = wp0b + (size_t)H3_ * H_;
  float* wp1b    = wp1f + (size_t)H3_ * H_;

  adm_mlp_kernel<<<1, 256, 0, stream>>>(adm, aW1, ab1, aW2, ab2, adm_out);
  embed_kernel<<<(NL_ * IN0_) / 256, 256, 0, stream>>>(series, mask, sW, membW, emb);
  whh_pack_kernel<<<(H3_ * H_) / 256, 256, 0, stream>>>(Whh0f, wp0f);
  whh_pack_kernel<<<(H3_ * H_) / 256, 256, 0, stream>>>(Whh0b, wp0b);
  whh_pack_kernel<<<(H3_ * H_) / 256, 256, 0, stream>>>(Whh1f, wp1f);
  whh_pack_kernel<<<(H3_ * H_) / 256, 256, 0, stream>>>(Whh1b, wp1b);

  // layer 0
  xp_gemm_kernel<<<dim3(NL_ / 128, (2 * H3_) / 128), 256, 0, stream>>>(
      emb, IN0_, Wih0f, Wih0b, bih0f, bih0b, xp);
  gru_scan_kernel<<<32, H3_, 0, stream>>>(xp, wp0f, wp0b, bhh0f, bhh0b, hcat);

  // layer 1 (xp buffer reused; hcat overwritten in place by scan output)
  xp_gemm_kernel<<<dim3(NL_ / 128, (2 * H3_) / 128), 256, 0, stream>>>(
      hcat, IN1_, Wih1f, Wih1b, bih1f, bih1b, xp);
  gru_scan_kernel<<<32, H3_, 0, stream>>>(xp, wp1f, wp1b, bhh1f, bhh1b, hcat);

  // fused FFN
  ffn_kernel<<<dim3(NL_ / 128, D_), 256, 0, stream>>>(
      hcat, adm_out, ffnW1, ffnb1, lng, lnb, ffnW2, ffnb2, outp);
}

// Round 4
// 2691.576 us; speedup vs baseline: 4.3346x; 4.3346x over previous
//
#include <hip/hip_runtime.h>
#include <math.h>

// ---------------------------------------------------------------------------
// MultiModalImputer forward.
// R3 change: gru_scan uses f16-packed Whh held in VGPRs (96 uint32/thread,
// fits under the 9-wave/block VGPR cap of ~168 that spilled R2's f32 array),
// v_dot2_f32_f16 for the recurrent dot (f32 accumulate), f16 h in LDS
// (halved broadcast reads), h_prev in a register of its owning thread.
// Everything else identical to the R0 baseline (5536 us).
// ---------------------------------------------------------------------------

constexpr int N_   = 16;
constexpr int L_   = 1024;
constexpr int D_   = 12;
constexpr int E_   = 8;
constexpr int HID_ = 16;
constexpr int ADM_ = 64;
constexpr int H_   = 192;   // HID*D
constexpr int H3_  = 576;   // 3*H
constexpr int IN0_ = 96;    // D*E
constexpr int IN1_ = 384;   // 2*H
constexpr int NL_  = N_ * L_;  // 16384
constexpr int FFH_ = 512;

#define F4(p) (*(const float4*)(p))

typedef _Float16 half2v __attribute__((ext_vector_type(2)));
union U32H2 { unsigned int u; half2v h; };
union H16U { _Float16 f; unsigned short s; };

__device__ __forceinline__ float dot2acc(unsigned int wu, unsigned int hu, float acc) {
#if __has_builtin(__builtin_amdgcn_fdot2)
  U32H2 a, b; a.u = wu; b.u = hu;
  return __builtin_amdgcn_fdot2(a.h, b.h, acc, false);
#else
  U32H2 a, b; a.u = wu; b.u = hu;
  acc = fmaf((float)a.h.x, (float)b.h.x, acc);
  return fmaf((float)a.h.y, (float)b.h.y, acc);
#endif
}

// ---------------- K1: adm MLP: relu(adm@W1.T+b1)@W2.T+b2 -> [16,16] --------
__global__ void adm_mlp_kernel(const float* __restrict__ adm,
                               const float* __restrict__ W1, const float* __restrict__ b1,
                               const float* __restrict__ W2, const float* __restrict__ b2,
                               float* __restrict__ adm_out) {
  __shared__ float hid[N_][HID_];
  const int t = threadIdx.x;        // 256
  const int n = t >> 4, j = t & 15;
  float acc = b1[j];
  for (int k = 0; k < ADM_; ++k) acc = fmaf(adm[n * ADM_ + k], W1[j * ADM_ + k], acc);
  hid[n][j] = fmaxf(acc, 0.f);
  __syncthreads();
  float acc2 = b2[j];
  for (int k = 0; k < HID_; ++k) acc2 = fmaf(hid[n][k], W2[j * HID_ + k], acc2);
  adm_out[n * HID_ + j] = acc2;
}

// ---------------- K2: fused mask-embedding + per-channel Linear(1->8) ------
__global__ void embed_kernel(const float* __restrict__ series, const int* __restrict__ mask,
                             const float* __restrict__ sW, const float* __restrict__ membW,
                             float* __restrict__ emb) {
  const int i = blockIdx.x * blockDim.x + threadIdx.x;   // over NL*96
  if (i >= NL_ * IN0_) return;
  const int de = i % IN0_;
  const int nl = i / IN0_;
  const int d = de >> 3, e = de & 7;
  const float s = series[nl * D_ + d];
  const int   m = mask[nl * D_ + d];
  const int idx = m ? (d + 1) : 0;
  emb[i] = membW[idx * E_ + e] + s * sW[de];
}

// ------- K3: pack Whh [576][192] f32 -> [24][576][4] uint32 (f16 pairs) ----
// out[((kc*576 + j)*4 + c)] packs k = kc*8 + c*2 and k+1 of row j.
__global__ void whh_pack16_kernel(const float* __restrict__ Whh, unsigned int* __restrict__ Wp) {
  const int o = blockIdx.x * blockDim.x + threadIdx.x;   // 576*96 = 55296
  if (o >= H3_ * 96) return;
  const int c  = o & 3;
  const int j  = (o >> 2) % H3_;
  const int kc = (o >> 2) / H3_;
  const int k  = kc * 8 + c * 2;
  H16U lo, hi;
  lo.f = (_Float16)Whh[j * H_ + k];
  hi.f = (_Float16)Whh[j * H_ + k + 1];
  Wp[o] = (unsigned int)lo.s | ((unsigned int)hi.s << 16);
}

// ---------------- K4: xp GEMM: xp[dir][row][j] = A@W^T + bih ---------------
// A [NL][K] row-major, Wf/Wb [576][K] row-major. BM=BN=128, BK=16, 8x8/thread.
__global__ __launch_bounds__(256)
void xp_gemm_kernel(const float* __restrict__ A, const int K,
                    const float* __restrict__ Wf, const float* __restrict__ Wb,
                    const float* __restrict__ bf, const float* __restrict__ bb,
                    float* __restrict__ xp /* [2][NL][576] */) {
  constexpr int BM = 128, BN = 128, BK = 16, TM = 8, TN = 8;
  __shared__ float As[BK][BM + 4];
  __shared__ float Bs[BK][BN + 4];
  const int bm = blockIdx.x;   // 128
  const int bn = blockIdx.y;   // 9
  const int t = threadIdx.x;
  const int tx = t & 15, ty = t >> 4;
  const int row0 = bm * BM, col0 = bn * BN;
  float acc[TM][TN] = {};

  for (int k0 = 0; k0 < K; k0 += BK) {
    #pragma unroll
    for (int r = 0; r < 2; ++r) {
      const int li = t + r * 256;
      const int i = li >> 2;
      const int kc = (li & 3) << 2;
      float4 v = F4(A + (size_t)(row0 + i) * K + k0 + kc);
      As[kc + 0][i] = v.x; As[kc + 1][i] = v.y; As[kc + 2][i] = v.z; As[kc + 3][i] = v.w;
    }
    #pragma unroll
    for (int r = 0; r < 2; ++r) {
      const int li = t + r * 256;
      const int jj = li >> 2;
      const int kc = (li & 3) << 2;
      const int col = col0 + jj;
      const float* W = (col < H3_) ? Wf : Wb;
      const int wrow = (col < H3_) ? col : col - H3_;
      float4 v = F4(W + (size_t)wrow * K + k0 + kc);
      Bs[kc + 0][jj] = v.x; Bs[kc + 1][jj] = v.y; Bs[kc + 2][jj] = v.z; Bs[kc + 3][jj] = v.w;
    }
    __syncthreads();
    #pragma unroll
    for (int kk = 0; kk < BK; ++kk) {
      float a[TM], b[TN];
      const float4* a4 = (const float4*)&As[kk][ty * TM];
      const float4* b4 = (const float4*)&Bs[kk][tx * TN];
      float4 av0 = a4[0], av1 = a4[1], bv0 = b4[0], bv1 = b4[1];
      a[0]=av0.x; a[1]=av0.y; a[2]=av0.z; a[3]=av0.w; a[4]=av1.x; a[5]=av1.y; a[6]=av1.z; a[7]=av1.w;
      b[0]=bv0.x; b[1]=bv0.y; b[2]=bv0.z; b[3]=bv0.w; b[4]=bv1.x; b[5]=bv1.y; b[6]=bv1.z; b[7]=bv1.w;
      #pragma unroll
      for (int i = 0; i < TM; ++i)
        #pragma unroll
        for (int jq = 0; jq < TN; ++jq) acc[i][jq] = fmaf(a[i], b[jq], acc[i][jq]);
    }
    __syncthreads();
  }
  #pragma unroll
  for (int i = 0; i < TM; ++i) {
    const int row = row0 + ty * TM + i;
    #pragma unroll
    for (int jq = 0; jq < TN; ++jq) {
      const int col = col0 + tx * TN + jq;
      const int dir = (col >= H3_);
      const int jj = col - dir * H3_;
      const float bias = dir ? bb[jj] : bf[jj];
      xp[((size_t)dir * NL_ + row) * H3_ + jj] = acc[i][jq] + bias;
    }
  }
}

// ---------------- K5: GRU scan. One block per (dir, batch). 576 threads. ---
// f16-packed Whh row (96 uint32) register-resident; f16 h broadcast in LDS;
// fdot2 accumulate in f32; h_prev in owning thread's register.
__global__ __launch_bounds__(H3_, 1)
void gru_scan_kernel(const float* __restrict__ xp,            // [2][NL][576]
                     const unsigned int* __restrict__ Wpf,    // [24][576][4] f16-pairs
                     const unsigned int* __restrict__ Wpb,
                     const float* __restrict__ bhf,
                     const float* __restrict__ bhb,
                     float* __restrict__ hcat) {              // [NL][384]
  const int dir = blockIdx.x >> 4;
  const int n   = blockIdx.x & 15;
  const float* __restrict__ xpd = xp + ((size_t)dir * NL_ + (size_t)n * L_) * H3_;
  const unsigned int* __restrict__ Wp = dir ? Wpb : Wpf;
  const float* __restrict__ bh  = dir ? bhb : bhf;
  float* __restrict__ outd = hcat + (size_t)n * L_ * IN1_ + dir * H_;

  const int j = threadIdx.x;   // 0..575

  __shared__ __align__(16) unsigned int h16[96];   // 192 f16 h values
  __shared__ float gh_lds[H3_];
  __shared__ float xn_lds[H_];

  // full f16-packed row j of Whh in registers: 24 x uint4 = 96 VGPRs
  uint4 w[24];
  #pragma unroll
  for (int kc = 0; kc < 24; ++kc)
    w[kc] = ((const uint4*)Wp)[kc * H3_ + j];

  const float bj = bh[j];
  if (j < 96) h16[j] = 0u;
  float hprev = 0.f;                       // valid for j < H_
  __syncthreads();

  const uint4* __restrict__ h4 = (const uint4*)h16;
  const int ts = dir ? -1 : 1;
  int t = dir ? (L_ - 1) : 0;
  float xv = xpd[(size_t)t * H3_ + j];     // prefetched current step

  for (int tt = 0; tt < L_; ++tt) {
    float xvn = 0.f;
    if (tt + 1 < L_) xvn = xpd[(size_t)(t + ts) * H3_ + j];

    float a0 = bj, a1 = 0.f, a2 = 0.f, a3 = 0.f;
    #pragma unroll
    for (int kc = 0; kc < 24; ++kc) {
      uint4 hv = h4[kc];                   // broadcast: same addr across wave
      a0 = dot2acc(w[kc].x, hv.x, a0);
      a1 = dot2acc(w[kc].y, hv.y, a1);
      a2 = dot2acc(w[kc].z, hv.z, a2);
      a3 = dot2acc(w[kc].w, hv.w, a3);
    }
    float acc = (a0 + a1) + (a2 + a3);

    if (j < 2 * H_) acc += xv;
    gh_lds[j] = acc;
    if (j >= 2 * H_) xn_lds[j - 2 * H_] = xv;
    __syncthreads();

    if (j < H_) {
      const float r  = 1.f / (1.f + __expf(-gh_lds[j]));
      const float z  = 1.f / (1.f + __expf(-gh_lds[H_ + j]));
      const float nn = tanhf(xn_lds[j] + r * gh_lds[2 * H_ + j]);
      const float hnew = (1.f - z) * nn + z * hprev;
      hprev = hnew;
      H16U cv; cv.f = (_Float16)hnew;
      ((unsigned short*)h16)[j] = cv.s;    // ds_write_b16
      outd[(size_t)t * IN1_ + j] = hnew;
    }
    __syncthreads();

    xv = xvn;
    t += ts;
  }
}

// ---------------- K6: fused per-channel FFN + LayerNorm + ReLU + Linear ----
// Block: (d, 128 rows). 256 threads; thread owns W1 rows t and t+256 in regs.
__global__ __launch_bounds__(256)
void ffn_kernel(const float* __restrict__ hcat, const float* __restrict__ adm_out,
                const float* __restrict__ W1, const float* __restrict__ b1,
                const float* __restrict__ lng, const float* __restrict__ lnb,
                const float* __restrict__ W2, const float* __restrict__ b2,
                float* __restrict__ out) {
  constexpr int FROWS = 8;
  const int d = blockIdx.y;            // 12
  const int row_base = blockIdx.x * 128;
  const int t = threadIdx.x;
  const int lane = t & 63, w = t >> 6;

  __shared__ __align__(16) float featL[FROWS][48];
  __shared__ __align__(16) float hhL[FROWS][FFH_];
  __shared__ float gL[FFH_], bLn[FFH_], w2L[FFH_], b1L[FFH_];

  for (int i = t; i < FFH_; i += 256) {
    gL[i]  = lng[d * FFH_ + i];
    bLn[i] = lnb[d * FFH_ + i];
    w2L[i] = W2[d * FFH_ + i];
    b1L[i] = b1[d * FFH_ + i];
  }
  float w1a[48], w1b[48];
  {
    const float* ra = W1 + ((size_t)d * FFH_ + t) * 48;
    const float* rb = W1 + ((size_t)d * FFH_ + 256 + t) * 48;
    #pragma unroll
    for (int kc = 0; kc < 12; ++kc) {
      float4 va = F4(ra + kc * 4);
      w1a[4*kc+0]=va.x; w1a[4*kc+1]=va.y; w1a[4*kc+2]=va.z; w1a[4*kc+3]=va.w;
      float4 vb = F4(rb + kc * 4);
      w1b[4*kc+0]=vb.x; w1b[4*kc+1]=vb.y; w1b[4*kc+2]=vb.z; w1b[4*kc+3]=vb.w;
    }
  }
  const float b2v = b2[d];
  __syncthreads();

  for (int c0 = 0; c0 < 128; c0 += FROWS) {
    for (int idx = t; idx < FROWS * 48; idx += 256) {
      const int r = idx / 48, k = idx % 48;
      const int row = row_base + c0 + r;
      float v;
      if (k < 32) v = hcat[(size_t)row * IN1_ + d * 32 + k];
      else        v = adm_out[(row >> 10) * HID_ + (k - 32)];
      featL[r][k] = v;
    }
    __syncthreads();
    float acc_a[FROWS] = {}, acc_b[FROWS] = {};
    #pragma unroll
    for (int r = 0; r < FROWS; ++r) {
      const float4* f4 = (const float4*)featL[r];
      #pragma unroll
      for (int kc = 0; kc < 12; ++kc) {
        float4 f = f4[kc];
        acc_a[r] = fmaf(w1a[4*kc+0], f.x, acc_a[r]);
        acc_a[r] = fmaf(w1a[4*kc+1], f.y, acc_a[r]);
        acc_a[r] = fmaf(w1a[4*kc+2], f.z, acc_a[r]);
        acc_a[r] = fmaf(w1a[4*kc+3], f.w, acc_a[r]);
        acc_b[r] = fmaf(w1b[4*kc+0], f.x, acc_b[r]);
        acc_b[r] = fmaf(w1b[4*kc+1], f.y, acc_b[r]);
        acc_b[r] = fmaf(w1b[4*kc+2], f.z, acc_b[r]);
        acc_b[r] = fmaf(w1b[4*kc+3], f.w, acc_b[r]);
      }
    }
    #pragma unroll
    for (int r = 0; r < FROWS; ++r) {
      hhL[r][t]       = acc_a[r] + b1L[t];
      hhL[r][t + 256] = acc_b[r] + b1L[t + 256];
    }
    __syncthreads();
    // LayerNorm + ReLU + W2 reduce: wave w handles rows w and w+4
    #pragma unroll
    for (int rr = 0; rr < 2; ++rr) {
      const int r = w + rr * 4;
      const float4* h4 = (const float4*)hhL[r];
      float4 x0 = h4[lane * 2], x1 = h4[lane * 2 + 1];
      float s = x0.x + x0.y + x0.z + x0.w + x1.x + x1.y + x1.z + x1.w;
      float q = x0.x*x0.x + x0.y*x0.y + x0.z*x0.z + x0.w*x0.w
              + x1.x*x1.x + x1.y*x1.y + x1.z*x1.z + x1.w*x1.w;
      #pragma unroll
      for (int m = 1; m < 64; m <<= 1) { s += __shfl_xor(s, m); q += __shfl_xor(q, m); }
      const float mu   = s * (1.f / FFH_);
      const float var  = q * (1.f / FFH_) - mu * mu;
      const float rstd = rsqrtf(var + 1e-5f);
      const int col = lane * 8;
      const float xs[8] = {x0.x, x0.y, x0.z, x0.w, x1.x, x1.y, x1.z, x1.w};
      float o = 0.f;
      #pragma unroll
      for (int i = 0; i < 8; ++i) {
        float v = (xs[i] - mu) * rstd * gL[col + i] + bLn[col + i];
        v = fmaxf(v, 0.f);
        o = fmaf(v, w2L[col + i], o);
      }
      #pragma unroll
      for (int m = 1; m < 64; m <<= 1) o += __shfl_xor(o, m);
      if (lane == 0) {
        const int row = row_base + c0 + r;
        out[(size_t)row * D_ + d] = o + b2v;
      }
    }
    __syncthreads();
  }
}

// ---------------------------------------------------------------------------
extern "C" void kernel_launch(void* const* d_in, const int* in_sizes, int n_in,
                              void* d_out, int out_size, void* d_ws, size_t ws_size,
                              hipStream_t stream) {
  const float* series = (const float*)d_in[0];
  const float* adm    = (const float*)d_in[1];
  const int*   mask   = (const int*)  d_in[2];
  const float* sW     = (const float*)d_in[3];
  const float* membW  = (const float*)d_in[4];
  const float* aW1    = (const float*)d_in[5];
  const float* ab1    = (const float*)d_in[6];
  const float* aW2    = (const float*)d_in[7];
  const float* ab2    = (const float*)d_in[8];
  const float* Wih0f  = (const float*)d_in[9];
  const float* Whh0f  = (const float*)d_in[10];
  const float* bih0f  = (const float*)d_in[11];
  const float* bhh0f  = (const float*)d_in[12];
  const float* Wih0b  = (const float*)d_in[13];
  const float* Whh0b  = (const float*)d_in[14];
  const float* bih0b  = (const float*)d_in[15];
  const float* bhh0b  = (const float*)d_in[16];
  const float* Wih1f  = (const float*)d_in[17];
  const float* Whh1f  = (const float*)d_in[18];
  const float* bih1f  = (const float*)d_in[19];
  const float* bhh1f  = (const float*)d_in[20];
  const float* Wih1b  = (const float*)d_in[21];
  const float* Whh1b  = (const float*)d_in[22];
  const float* bih1b  = (const float*)d_in[23];
  const float* bhh1b  = (const float*)d_in[24];
  const float* ffnW1  = (const float*)d_in[25];
  const float* ffnb1  = (const float*)d_in[26];
  const float* lng    = (const float*)d_in[27];
  const float* lnb    = (const float*)d_in[28];
  const float* ffnW2  = (const float*)d_in[29];
  const float* ffnb2  = (const float*)d_in[30];
  float* outp = (float*)d_out;

  // workspace layout (floats)
  float* ws      = (float*)d_ws;
  float* adm_out = ws;                                   // 256
  float* emb     = adm_out + 256;                        // NL*96   = 1,572,864
  float* xp      = emb + (size_t)NL_ * IN0_;             // 2*NL*576= 18,874,368
  float* hcat    = xp + (size_t)2 * NL_ * H3_;           // NL*384  = 6,291,456
  unsigned int* wp0f = (unsigned int*)(hcat + (size_t)NL_ * IN1_);  // 55,296 u32 each
  unsigned int* wp0b = wp0f + (size_t)H3_ * 96;
  unsigned int* wp1f = wp0b + (size_t)H3_ * 96;
  unsigned int* wp1b = wp1f + (size_t)H3_ * 96;

  adm_mlp_kernel<<<1, 256, 0, stream>>>(adm, aW1, ab1, aW2, ab2, adm_out);
  embed_kernel<<<(NL_ * IN0_) / 256, 256, 0, stream>>>(series, mask, sW, membW, emb);
  whh_pack16_kernel<<<(H3_ * 96) / 256, 256, 0, stream>>>(Whh0f, wp0f);
  whh_pack16_kernel<<<(H3_ * 96) / 256, 256, 0, stream>>>(Whh0b, wp0b);
  whh_pack16_kernel<<<(H3_ * 96) / 256, 256, 0, stream>>>(Whh1f, wp1f);
  whh_pack16_kernel<<<(H3_ * 96) / 256, 256, 0, stream>>>(Whh1b, wp1b);

  // layer 0
  xp_gemm_kernel<<<dim3(NL_ / 128, (2 * H3_) / 128), 256, 0, stream>>>(
      emb, IN0_, Wih0f, Wih0b, bih0f, bih0b, xp);
  gru_scan_kernel<<<32, H3_, 0, stream>>>(xp, wp0f, wp0b, bhh0f, bhh0b, hcat);

  // layer 1 (xp buffer reused; hcat overwritten in place by scan output)
  xp_gemm_kernel<<<dim3(NL_ / 128, (2 * H3_) / 128), 256, 0, stream>>>(
      hcat, IN1_, Wih1f, Wih1b, bih1f, bih1b, xp);
  gru_scan_kernel<<<32, H3_, 0, stream>>>(xp, wp1f, wp1b, bhh1f, bhh1b, hcat);

  // fused FFN
  ffn_kernel<<<dim3(NL_ / 128, D_), 256, 0, stream>>>(
      hcat, adm_out, ffnW1, ffnb1, lng, lnb, ffnW2, ffnb2, outp);
}